// Round 4
// baseline (479.510 us; speedup 1.0000x reference)
//
#include <hip/hip_runtime.h>
#include <hip/hip_bf16.h>

// Equivariant decoder: r=|v| -> MLP(fp32 tiled GEMMs, 4-wave blocks) -> r_dec bf16
//   -> t=einsum('bi,ijp') bf16 MFMA (K-split, 2 b-tiles/wave, 2j-dbuf LDS)
//   -> out_vec=einsum('bjp,bjm')/C fused in-register -> [P x 1o | Q zeros]
// Workspace layout (83.4 MB total):
//   [0, 67108864)         Wtp bf16, 32x32x16 A-fragment order
//   [67108864, 67633152)  r_dec bf16 [1024][256]
//   [67633152, 70778880)  vT fp32 [256 j][3 m][1024 b]
//   [70778880, 83361792)  part bf16 [4 js][1024 b][1536]   (MLP temps overlap here)

#define N_G   1024
#define C_DIM 256
#define P_DIM 512
#define F_DIM 768
#define OUT_STRIDE 6656
#define VEC_LEN 1536

typedef short  short8  __attribute__((ext_vector_type(8)));
typedef float  f32x16  __attribute__((ext_vector_type(16)));

#define GLOAD_LDS16(GP, LP)                                                    \
  __builtin_amdgcn_global_load_lds(                                            \
      (const __attribute__((address_space(1))) void*)(GP),                     \
      (__attribute__((address_space(3))) void*)(LP), 16, 0, 0)

static __device__ __forceinline__ unsigned short f32_bf16(float f){
  unsigned u = __builtin_bit_cast(unsigned, f);
  u = (u + 0x7fffu + ((u >> 16) & 1u)) >> 16;   // RNE
  return (unsigned short)u;
}
static __device__ __forceinline__ float bf16_f32(unsigned short u){
  return __builtin_bit_cast(float, (unsigned)u << 16);
}
static __device__ __forceinline__ float gelu_tanh(float x){
  float u = 0.7978845608028654f * (x + 0.044715f * x * x * x);
  return 0.5f * x * (1.0f + tanhf(u));
}

// ---------------- prepack: Wtp fp32 [i=256][j=256][p=512] -> bf16 A-fragment order
// unit = (j*16 + pt)*16 + ik ; lane p = pt*32+(lane&31), k = ik*16+(lane>>5)*8+e
__global__ __launch_bounds__(256) void k_prepack(const float* __restrict__ wtp,
                                                 unsigned short* __restrict__ frag){
  int tid  = blockIdx.x * 256 + threadIdx.x;
  int unit = tid >> 6, lane = tid & 63;
  int j  = unit >> 8;
  int pt = (unit >> 4) & 15;
  int ik = unit & 15;
  int p  = pt * 32 + (lane & 31);
  int i0 = ik * 16 + (lane >> 5) * 8;
  const float* src = wtp + (size_t)i0 * (C_DIM * P_DIM) + j * P_DIM + p;
  short8 v;
  #pragma unroll
  for (int e = 0; e < 8; ++e)
    v[e] = (short)f32_bf16(src[(size_t)e * (C_DIM * P_DIM)]);
  *reinterpret_cast<short8*>(frag + (size_t)unit * 512 + lane * 8) = v;
}

// ---------------- r = per-channel vector norms: [1024][256]
__global__ __launch_bounds__(256) void k_norm(const float* __restrict__ enc,
                                              float* __restrict__ r){
  int b = blockIdx.x, t = threadIdx.x;
  const float* e = enc + (size_t)b * F_DIM + t * 3;
  r[(size_t)b * C_DIM + t] = sqrtf(e[0]*e[0] + e[1]*e[1] + e[2]*e[2]);
}

// ---------------- vT[j][m][b] = enc[b][3j+m]  (coalesced v-loads for k_tp)
__global__ __launch_bounds__(256) void k_vt(const float* __restrict__ enc,
                                            float* __restrict__ vT){
  int tid = blockIdx.x * 256 + threadIdx.x;       // 786432 threads
  int b  = tid & 1023;
  int jm = tid >> 10;                             // 0..767
  int j  = jm / 3, m = jm - j * 3;
  vT[(size_t)j * 3072 + m * 1024 + b] = enc[(size_t)b * F_DIM + j * 3 + m];
}

// ---------------- tiled fp32 GEMM: C[M,N] = A[M,K]@B[K,N] + bias
// BM=32, BN=64, BK=64; 256 threads (4 waves); thread tile 2x4 (tr=t>>4, tc=t&15)
template<bool OBF>
__global__ __launch_bounds__(256) void k_gemm(const float* __restrict__ A,
    const float* __restrict__ B, const float* __restrict__ bias,
    float* __restrict__ C, unsigned short* __restrict__ Cb,
    int M, int N, int K){
  __shared__ __align__(16) float Ast[64][36];   // [kk][m], padded
  __shared__ __align__(16) float Bs[64][64];    // [kk][n]
  int nbc = N >> 6;
  int mb = blockIdx.x / nbc, nb = blockIdx.x % nbc;
  int m0 = mb * 32, n0 = nb * 64;
  int t  = threadIdx.x;
  int tr = t >> 4, tc = t & 15;

  float acc[2][4];
  #pragma unroll
  for (int i = 0; i < 2; ++i)
    #pragma unroll
    for (int q = 0; q < 4; ++q) acc[i][q] = 0.f;

  for (int kc = 0; kc < K; kc += 64){
    { // stage A[32][64] transposed -> Ast[kk][m]; 8 floats per thread, coalesced
      int m = t >> 3, k0 = (t & 7) * 8;
      const float* ap = A + (size_t)(m0 + m) * K + kc + k0;
      float4 a0 = *reinterpret_cast<const float4*>(ap);
      float4 a1 = *reinterpret_cast<const float4*>(ap + 4);
      Ast[k0+0][m] = a0.x; Ast[k0+1][m] = a0.y; Ast[k0+2][m] = a0.z; Ast[k0+3][m] = a0.w;
      Ast[k0+4][m] = a1.x; Ast[k0+5][m] = a1.y; Ast[k0+6][m] = a1.z; Ast[k0+7][m] = a1.w;
    }
    { // stage B[64][64] -> Bs; 16 floats per thread, coalesced
      int kk = t >> 2, nc = (t & 3) * 16;
      const float* bp = B + (size_t)(kc + kk) * N + n0 + nc;
      float4* d = reinterpret_cast<float4*>(&Bs[kk][nc]);
      d[0] = reinterpret_cast<const float4*>(bp)[0];
      d[1] = reinterpret_cast<const float4*>(bp)[1];
      d[2] = reinterpret_cast<const float4*>(bp)[2];
      d[3] = reinterpret_cast<const float4*>(bp)[3];
    }
    __syncthreads();
    #pragma unroll 16
    for (int kk = 0; kk < 64; ++kk){
      float2 av = *reinterpret_cast<const float2*>(&Ast[kk][tr * 2]);
      float4 bv = *reinterpret_cast<const float4*>(&Bs[kk][tc * 4]);
      acc[0][0] += av.x*bv.x; acc[0][1] += av.x*bv.y; acc[0][2] += av.x*bv.z; acc[0][3] += av.x*bv.w;
      acc[1][0] += av.y*bv.x; acc[1][1] += av.y*bv.y; acc[1][2] += av.y*bv.z; acc[1][3] += av.y*bv.w;
    }
    __syncthreads();
  }

  #pragma unroll
  for (int i = 0; i < 2; ++i){
    int row = m0 + tr * 2 + i;
    #pragma unroll
    for (int q = 0; q < 4; ++q){
      int col = n0 + tc * 4 + q;
      float val = acc[i][q] + bias[col];
      if (OBF) Cb[(size_t)row * N + col] = f32_bf16(val);
      else     C [(size_t)row * N + col] = val;
    }
  }
}

// ---------------- LayerNorm + GELU over rows of 768: wave per row, 4 rows/block
__global__ __launch_bounds__(256) void k_ln(const float* __restrict__ X,
    const float* __restrict__ g, const float* __restrict__ be,
    float* __restrict__ Y){
  int w = threadIdx.x >> 6, lane = threadIdx.x & 63;
  int row = blockIdx.x * 4 + w;
  const float* x = X + (size_t)row * F_DIM;
  float v[12];
  float s = 0.f, s2 = 0.f;
  #pragma unroll
  for (int i = 0; i < 12; ++i){
    v[i] = x[lane + i * 64];
    s += v[i]; s2 += v[i] * v[i];
  }
  #pragma unroll
  for (int off = 32; off; off >>= 1){ s += __shfl_down(s, off); s2 += __shfl_down(s2, off); }
  s = __shfl(s, 0); s2 = __shfl(s2, 0);
  float mu = s * (1.0f / F_DIM);
  float rs = rsqrtf(s2 * (1.0f / F_DIM) - mu * mu + 1e-5f);
  float* y = Y + (size_t)row * F_DIM;
  #pragma unroll
  for (int i = 0; i < 12; ++i){
    int c = lane + i * 64;
    y[c] = gelu_tanh((v[i] - mu) * rs * g[c] + be[c]);
  }
}

// ---------------- main fused TP, K-split + 2 b-tiles per wave.
// grid 256 = pt(16) x bblk(4) x js(4); block 512 = 8 waves = 4 bg x 2 kh.
// Wave: p-tile pt (32 p), b = bblk*256 + bg*64 + bt*32 + (lane&31) (bt=0,1),
//       K-half kh (i in kh*128..+128). Each A-fragment read feeds 2 MFMAs.
__global__ __launch_bounds__(512, 2) void k_tp(const unsigned short* __restrict__ frag,
    const unsigned short* __restrict__ rdec, const float* __restrict__ vT,
    unsigned short* __restrict__ part){
  __shared__ __align__(16) unsigned short As[2][16384];   // 2 bufs x (2 j x 16 KB)
  int bx   = blockIdx.x;
  int pt   = bx & 15;
  int bblk = (bx >> 4) & 3;
  int js   = bx >> 6;
  int w    = threadIdx.x >> 6;
  int lane = threadIdx.x & 63;
  int bg   = w >> 1, kh = w & 1;
  int g    = lane >> 5;
  int b0   = bblk * 256 + bg * 64 + (lane & 31);

  // resident B-fragments: 2 b-tiles x 8 K-chunks (this wave's K-half) = 64 VGPR
  short8 bf[2][8];
  #pragma unroll
  for (int bt = 0; bt < 2; ++bt)
    #pragma unroll
    for (int k = 0; k < 8; ++k)
      bf[bt][k] = *reinterpret_cast<const short8*>(
          rdec + (size_t)(b0 + bt * 32) * C_DIM + (kh * 8 + k) * 16 + g * 8);

  float oacc[2][48];
  #pragma unroll
  for (int bt = 0; bt < 2; ++bt)
    #pragma unroll
    for (int q = 0; q < 48; ++q) oacc[bt][q] = 0.f;

  int j0 = js * 64;
  // stage 2 j-tiles (32 units x 1KB) into As[buf]; 4 units/wave; linear dest
  #define STAGE2(BUF, J) do {                                                      \
    _Pragma("unroll")                                                              \
    for (int uu = 0; uu < 4; ++uu){                                                \
      int u = w * 4 + uu;                                                          \
      const unsigned short* gp = frag +                                            \
          ((size_t)((((J) + (u >> 4)) * 16 + pt) * 16 + (u & 15))) * 512 + lane*8; \
      GLOAD_LDS16(gp, &As[BUF][u * 512]);                                          \
    } } while (0)

  STAGE2(0, j0);
  __syncthreads();
  int cur = 0;
  for (int jj = j0; jj < j0 + 64; jj += 2){
    if (jj + 2 < j0 + 64) STAGE2(cur ^ 1, jj + 2);
    #pragma unroll
    for (int jl = 0; jl < 2; ++jl){
      const unsigned short* ab = &As[cur][(jl * 16 + kh * 8) * 512 + lane * 8];
      short8 af[8];
      #pragma unroll
      for (int k = 0; k < 8; ++k)
        af[k] = *reinterpret_cast<const short8*>(ab + k * 512);
      f32x16 acc0 = {}, acc1 = {};
      #pragma unroll
      for (int k = 0; k < 8; ++k){
        acc0 = __builtin_amdgcn_mfma_f32_32x32x16_bf16(af[k], bf[0][k], acc0, 0, 0, 0);
        acc1 = __builtin_amdgcn_mfma_f32_32x32x16_bf16(af[k], bf[1][k], acc1, 0, 0, 0);
      }
      const float* vp = vT + (size_t)(jj + jl) * 3072;
      float v00 = vp[b0], v01 = vp[1024 + b0], v02 = vp[2048 + b0];
      float v10 = vp[b0 + 32], v11 = vp[1024 + b0 + 32], v12 = vp[2048 + b0 + 32];
      #pragma unroll
      for (int r = 0; r < 16; ++r){
        oacc[0][r*3+0] += acc0[r]*v00; oacc[0][r*3+1] += acc0[r]*v01; oacc[0][r*3+2] += acc0[r]*v02;
        oacc[1][r*3+0] += acc1[r]*v10; oacc[1][r*3+1] += acc1[r]*v11; oacc[1][r*3+2] += acc1[r]*v12;
      }
    }
    __syncthreads();
    cur ^= 1;
  }

  // K-half pair-reduce through LDS (2 rounds x 48KB), then kh==0 writes part
  float* red = (float*)As;
  int rb = bg >> 1;
  #pragma unroll
  for (int round = 0; round < 2; ++round){
    __syncthreads();
    if (kh == 1 && rb == round){
      int chunk = (bg & 1) * 2;
      #pragma unroll
      for (int bt = 0; bt < 2; ++bt){
        float* dst = red + ((size_t)((chunk + bt) * 64 + lane)) * 48;
        #pragma unroll
        for (int q = 0; q < 48; ++q) dst[q] = oacc[bt][q];
      }
    }
    __syncthreads();
    if (kh == 0 && rb == round){
      int chunk = (bg & 1) * 2;
      #pragma unroll
      for (int bt = 0; bt < 2; ++bt){
        const float* src = red + ((size_t)((chunk + bt) * 64 + lane)) * 48;
        #pragma unroll
        for (int q = 0; q < 48; ++q) oacc[bt][q] += src[q];
      }
    }
  }
  if (kh == 0){
    #pragma unroll
    for (int bt = 0; bt < 2; ++bt){
      unsigned short* pb = part + ((size_t)js * N_G + (b0 + bt * 32)) * VEC_LEN;
      #pragma unroll
      for (int r = 0; r < 16; ++r){
        int p = pt * 32 + (r & 3) + 8 * (r >> 2) + 4 * g;   // verified C/D row map
        pb[p*3+0] = f32_bf16(oacc[bt][r*3+0]);
        pb[p*3+1] = f32_bf16(oacc[bt][r*3+1]);
        pb[p*3+2] = f32_bf16(oacc[bt][r*3+2]);
      }
    }
  }
}

// ---------------- reduce 4 bf16 j-partials * (1/C), write structural zeros
__global__ __launch_bounds__(256) void k_reduce(const unsigned short* __restrict__ part,
                                                float* __restrict__ out){
  int idx = blockIdx.x * 256 + threadIdx.x;
  if (idx >= N_G * OUT_STRIDE) return;
  int b = idx / OUT_STRIDE;
  int q = idx - b * OUT_STRIDE;
  float val = 0.f;
  if (q < VEC_LEN){
    size_t base = (size_t)b * VEC_LEN + q;
    const size_t st = (size_t)N_G * VEC_LEN;
    val = (bf16_f32(part[base]) + bf16_f32(part[base + st]) +
           bf16_f32(part[base + 2*st]) + bf16_f32(part[base + 3*st])) * (1.0f / C_DIM);
  }
  out[idx] = val;
}

extern "C" void kernel_launch(void* const* d_in, const int* in_sizes, int n_in,
                              void* d_out, int out_size, void* d_ws, size_t ws_size,
                              hipStream_t stream){
  const float* enc  = (const float*)d_in[0];
  const float* W0   = (const float*)d_in[1];
  const float* b0   = (const float*)d_in[2];
  const float* g0   = (const float*)d_in[3];
  const float* be0  = (const float*)d_in[4];
  const float* W1   = (const float*)d_in[5];
  const float* b1   = (const float*)d_in[6];
  const float* g1   = (const float*)d_in[7];
  const float* be1  = (const float*)d_in[8];
  const float* Wout = (const float*)d_in[9];
  const float* bout = (const float*)d_in[10];
  const float* Wtp  = (const float*)d_in[11];
  float* out = (float*)d_out;

  char* ws = (char*)d_ws;
  unsigned short* frag = (unsigned short*)(ws);                 // 64 MB
  unsigned short* rdec = (unsigned short*)(ws + 67108864);      // 512 KB
  float*          vT   = (float*)(ws + 67633152);               // 3 MB
  unsigned short* part = (unsigned short*)(ws + 70778880);      // 12.6 MB
  // MLP temps overlap the part region (dead before k_tp writes part):
  float* rbuf = (float*)(ws + 70778880);                        // 1 MB
  float* bufA = (float*)(ws + 70778880 + 1048576);              // 3 MB
  float* bufB = (float*)(ws + 70778880 + 1048576 + 3145728);    // 3 MB

  hipLaunchKernelGGL(k_prepack, dim3(16384), dim3(256), 0, stream, Wtp, frag);
  hipLaunchKernelGGL(k_norm,    dim3(N_G),   dim3(256), 0, stream, enc, rbuf);
  hipLaunchKernelGGL(k_vt,      dim3(3072),  dim3(256), 0, stream, enc, vT);
  hipLaunchKernelGGL((k_gemm<false>), dim3(32 * 12), dim3(256), 0, stream,
                     rbuf, W0, b0, bufA, rdec, N_G, F_DIM, C_DIM);
  hipLaunchKernelGGL(k_ln,      dim3(256),   dim3(256), 0, stream, bufA, g0, be0, bufB);
  hipLaunchKernelGGL((k_gemm<false>), dim3(32 * 12), dim3(256), 0, stream,
                     bufB, W1, b1, bufA, rdec, N_G, F_DIM, F_DIM);
  hipLaunchKernelGGL(k_ln,      dim3(256),   dim3(256), 0, stream, bufA, g1, be1, bufB);
  hipLaunchKernelGGL((k_gemm<true>),  dim3(32 * 4),  dim3(256), 0, stream,
                     bufB, Wout, bout, bufA, rdec, N_G, C_DIM, F_DIM);
  hipLaunchKernelGGL(k_tp,      dim3(256),   dim3(512), 0, stream, frag, rdec, vT, part);
  hipLaunchKernelGGL(k_reduce,  dim3((N_G * OUT_STRIDE + 255) / 256), dim3(256), 0, stream,
                     part, out);
}